// Round 1
// baseline (40.969 us; speedup 1.0000x reference)
//
#include <hip/hip_runtime.h>

#define NPART 8192

// Partial-sum kernel: block (bi, bj) computes, for each of 256 particles i in
// i-tile bi, the partial density contribution from the jchunk particles in
// j-tile bj. j-positions staged in LDS (broadcast reads: all lanes read the
// same address per iteration -> conflict-free).
__global__ __launch_bounds__(256) void sph_partial(const float* __restrict__ pos,
                                                   float* __restrict__ ws,
                                                   int jchunk) {
    extern __shared__ float sj[];
    const int i  = blockIdx.x * 256 + threadIdx.x;
    const int j0 = blockIdx.y * jchunk;

    // Stage j-tile into LDS with float4 loads (base byte offset j0*12 is
    // 16B-aligned for jchunk multiple of 4... jchunk*12 % 16 == 0 for
    // jchunk % 4 == 0, and blockIdx.y*jchunk*12 is then 16B-aligned too
    // when jchunk is a multiple of 4 -- jchunk is 128 here).
    const float4* src = (const float4*)(pos + (size_t)j0 * 3);
    float4*       dst = (float4*)sj;
    const int nvec = jchunk * 3 / 4;
    for (int t = threadIdx.x; t < nvec; t += 256) dst[t] = src[t];
    __syncthreads();

    const float xi = pos[3 * i + 0];
    const float yi = pos[3 * i + 1];
    const float zi = pos[3 * i + 2];

    const float inv_h = 10.0f;  // 1 / 0.1
    float acc = 0.0f;

#pragma unroll 8
    for (int j = 0; j < jchunk; ++j) {
        float dx = sj[3 * j + 0] - xi;
        float dy = sj[3 * j + 1] - yi;
        float dz = sj[3 * j + 2] - zi;
        float d2 = fmaf(dx, dx, fmaf(dy, dy, fmaf(dz, dz, 1e-10f)));
        float q  = __builtin_amdgcn_sqrtf(d2) * inv_h;   // q = r/h
        float t  = 1.0f - q;
        // w_inner = 1 - 6q^2 + 6q^3 = 1 - 6 q^2 (1 - q)
        float w_in  = fmaf(-6.0f * q * q, t, 1.0f);
        // w_outer = 2 (1-q)^3
        float w_out = 2.0f * t * t * t;
        float w = (q <= 0.5f) ? w_in : w_out;
        w = (q <= 1.0f) ? w : 0.0f;
        acc += w;
    }

    ws[(size_t)blockIdx.y * NPART + i] = acc;
}

// Reduce the nsplit partials per particle and apply mass * norm_const.
__global__ __launch_bounds__(256) void sph_reduce(const float* __restrict__ ws,
                                                  float* __restrict__ out,
                                                  int nsplit) {
    const int i = blockIdx.x * 256 + threadIdx.x;
    float s = 0.0f;
    for (int k = 0; k < nsplit; ++k) s += ws[(size_t)k * NPART + i];
    // MASS * 8 / (PI * H^3), PI exactly as the reference literal
    const float norm = (float)(8.0 / (3.14159265 * 0.1 * 0.1 * 0.1));
    out[i] = s * norm;
}

extern "C" void kernel_launch(void* const* d_in, const int* in_sizes, int n_in,
                              void* d_out, int out_size, void* d_ws, size_t ws_size,
                              hipStream_t stream) {
    const float* pos = (const float*)d_in[0];
    float*       out = (float*)d_out;
    float*       ws  = (float*)d_ws;

    // 64 j-splits -> 2048 blocks (good CU coverage); degrade if ws is small.
    int nsplit = 64;
    while (nsplit > 1 && (size_t)nsplit * NPART * sizeof(float) > ws_size)
        nsplit >>= 1;
    const int jchunk = NPART / nsplit;

    dim3 grid(NPART / 256, nsplit);
    size_t lds_bytes = (size_t)jchunk * 3 * sizeof(float);
    sph_partial<<<grid, 256, lds_bytes, stream>>>(pos, ws, jchunk);
    sph_reduce<<<NPART / 256, 256, 0, stream>>>(ws, out, nsplit);
}

// Round 2
// 27.000 us; speedup vs baseline: 1.5174x; 1.5174x over previous
//
#include <hip/hip_runtime.h>

#define NPART 8192

// Pair-interaction kernel with whole-wave early exit.
// Block (bi, bj): 256 i-particles vs jchunk j-particles staged in LDS.
// Cubic spline identity: w(q) = 2*max(1-q,0)^3 - max(1-2q,0)^3
//   (== 1-6q^2+6q^3 for q<=0.5; 2(1-q)^3 for 0.5<q<=1; 0 for q>1).
// With q = r/h, h=0.1:  a = max(1-10r,0), b = max(1-20r,0), w = 2a^3 - b^3.
// Contribution is exactly 0 for r^2 > 0.01, so a wave skips the sqrt+poly
// whenever no lane has any of its 4 candidate pairs inside the cutoff.
__global__ __launch_bounds__(256) void sph_partial(const float* __restrict__ pos,
                                                   float* __restrict__ ws,
                                                   int jchunk) {
    extern __shared__ float sj[];
    const int i  = blockIdx.x * 256 + threadIdx.x;
    const int j0 = blockIdx.y * jchunk;

    // Stage j-tile into LDS with float4 loads (offsets 16B-aligned: jchunk
    // and j0 are multiples of 4 -> byte offset 12*j0 % 16 == 0).
    const float4* src = (const float4*)(pos + (size_t)j0 * 3);
    float4*       dst = (float4*)sj;
    const int nvec = jchunk * 3 / 4;
    for (int t = threadIdx.x; t < nvec; t += 256) dst[t] = src[t];
    __syncthreads();

    const float xi = pos[3 * i + 0];
    const float yi = pos[3 * i + 1];
    const float zi = pos[3 * i + 2];

    const float RCUT2 = 0.0100001f;  // (h=0.1)^2 with margin; w==0 beyond
    float acc1 = 0.0f;   // sum of a^3
    float acc2 = 0.0f;   // sum of b^3

    for (int j = 0; j < jchunk; j += 4) {
        // 4 j-positions = 12 contiguous floats = 3 LDS float4 broadcasts
        const float4 p0 = *(const float4*)&sj[3 * j + 0];
        const float4 p1 = *(const float4*)&sj[3 * j + 4];
        const float4 p2 = *(const float4*)&sj[3 * j + 8];

        const float dx0 = p0.x - xi, dy0 = p0.y - yi, dz0 = p0.z - zi;
        const float dx1 = p0.w - xi, dy1 = p1.x - yi, dz1 = p1.y - zi;
        const float dx2 = p1.z - xi, dy2 = p1.w - yi, dz2 = p2.x - zi;
        const float dx3 = p2.y - xi, dy3 = p2.z - yi, dz3 = p2.w - zi;

        const float d20 = fmaf(dx0, dx0, fmaf(dy0, dy0, fmaf(dz0, dz0, 1e-10f)));
        const float d21 = fmaf(dx1, dx1, fmaf(dy1, dy1, fmaf(dz1, dz1, 1e-10f)));
        const float d22 = fmaf(dx2, dx2, fmaf(dy2, dy2, fmaf(dz2, dz2, 1e-10f)));
        const float d23 = fmaf(dx3, dx3, fmaf(dy3, dy3, fmaf(dz3, dz3, 1e-10f)));

        const float m = fminf(fminf(d20, d21), fminf(d22, d23));
        if (__any(m <= RCUT2)) {
            // Slow path (rare): clamped cubics; far lanes contribute 0 via max.
            {
                const float r = __builtin_amdgcn_sqrtf(d20);
                const float a = fmaxf(fmaf(-10.0f, r, 1.0f), 0.0f);
                const float b = fmaxf(fmaf(-20.0f, r, 1.0f), 0.0f);
                acc1 = fmaf(a * a, a, acc1);
                acc2 = fmaf(b * b, b, acc2);
            }
            {
                const float r = __builtin_amdgcn_sqrtf(d21);
                const float a = fmaxf(fmaf(-10.0f, r, 1.0f), 0.0f);
                const float b = fmaxf(fmaf(-20.0f, r, 1.0f), 0.0f);
                acc1 = fmaf(a * a, a, acc1);
                acc2 = fmaf(b * b, b, acc2);
            }
            {
                const float r = __builtin_amdgcn_sqrtf(d22);
                const float a = fmaxf(fmaf(-10.0f, r, 1.0f), 0.0f);
                const float b = fmaxf(fmaf(-20.0f, r, 1.0f), 0.0f);
                acc1 = fmaf(a * a, a, acc1);
                acc2 = fmaf(b * b, b, acc2);
            }
            {
                const float r = __builtin_amdgcn_sqrtf(d23);
                const float a = fmaxf(fmaf(-10.0f, r, 1.0f), 0.0f);
                const float b = fmaxf(fmaf(-20.0f, r, 1.0f), 0.0f);
                acc1 = fmaf(a * a, a, acc1);
                acc2 = fmaf(b * b, b, acc2);
            }
        }
    }

    // Unscaled kernel sum for this j-tile: sum(2a^3 - b^3)
    ws[(size_t)blockIdx.y * NPART + i] = fmaf(2.0f, acc1, -acc2);
}

// Reduce the nsplit partials per particle and apply mass * norm_const.
__global__ __launch_bounds__(256) void sph_reduce(const float* __restrict__ ws,
                                                  float* __restrict__ out,
                                                  int nsplit) {
    const int i = blockIdx.x * 256 + threadIdx.x;
    float s = 0.0f;
    for (int k = 0; k < nsplit; ++k) s += ws[(size_t)k * NPART + i];
    // MASS * 8 / (PI * H^3), PI exactly as the reference literal
    const float norm = (float)(8.0 / (3.14159265 * 0.1 * 0.1 * 0.1));
    out[i] = s * norm;
}

extern "C" void kernel_launch(void* const* d_in, const int* in_sizes, int n_in,
                              void* d_out, int out_size, void* d_ws, size_t ws_size,
                              hipStream_t stream) {
    const float* pos = (const float*)d_in[0];
    float*       out = (float*)d_out;
    float*       ws  = (float*)d_ws;

    // 64 j-splits -> 2048 blocks (full CU coverage); degrade if ws is small.
    int nsplit = 64;
    while (nsplit > 1 && (size_t)nsplit * NPART * sizeof(float) > ws_size)
        nsplit >>= 1;
    const int jchunk = NPART / nsplit;

    dim3 grid(NPART / 256, nsplit);
    size_t lds_bytes = (size_t)jchunk * 3 * sizeof(float);
    sph_partial<<<grid, 256, lds_bytes, stream>>>(pos, ws, jchunk);
    sph_reduce<<<NPART / 256, 256, 0, stream>>>(ws, out, nsplit);
}